// Round 2
// baseline (655.061 us; speedup 1.0000x reference)
//
#include <hip/hip_runtime.h>
#include <hip/hip_bf16.h>
#include <cstdint>

// GroupFNO1d on MI355X.
// B=2048, E=16, S=512, W=512, M=64(modes), C=64, O=8. Rows N_ROWS = B*E = 32768.
// Spectral layer with only 64 kept rFFT modes == analysis GEMM (N=128 cos/-sin rows)
// + per-(e,k) complex mix + synthesis columns folded into the next weight matrix
// (K extended 1024 -> 1152). So the whole net is 3 big bf16 MFMA GEMMs + 2 skinny
// analysis GEMMs + a fused fc1/fc2 tail.
//
// Workspace is ws_size-ADAPTIVE (round-1 crash root cause: fixed 292MB layout
// could exceed ws_size -> device fault). Fixed weights ~6.8MB at front; rows
// processed in chunks of R (multiple of 128, capped at 16384 -> peak ~150MB).

typedef __bf16 bf16;
typedef __attribute__((ext_vector_type(8))) __bf16 bf16x8;
typedef __attribute__((ext_vector_type(4))) float f32x4;

#define N_ROWS 32768

__device__ __forceinline__ void gl_lds16(const void* g, void* l) {
    __builtin_amdgcn_global_load_lds(
        (const __attribute__((address_space(1))) void*)g,
        (__attribute__((address_space(3))) void*)l,
        16, 0, 0);
}

__device__ __forceinline__ float swishf(float v) {
    return v / (1.f + __expf(-v));
}

// ---------------- setup kernels ----------------

// cmix[e*64+k] = g_k * (lam_k*com_c[k] + (1-lam_k)*(codes@code)[e,k]),  g_0=1/1024, g_k=2/1024
__global__ __launch_bounds__(256) void build_cmix(const float* __restrict__ codes,
                                                  const float* __restrict__ com,
                                                  const float* __restrict__ code,
                                                  const float* __restrict__ filt,
                                                  float2* __restrict__ cmix) {
    int t = blockIdx.x * 256 + threadIdx.x;
    if (t >= 16 * 64) return;
    int e = t >> 6, m = t & 63;
    float er = 0.f, ei = 0.f;
    for (int c = 0; c < 64; ++c) {
        float cd = codes[e * 64 + c];
        er += cd * code[(c * 64 + m) * 2 + 0];
        ei += cd * code[(c * 64 + m) * 2 + 1];
    }
    float f = filt[m];
    float lam = fminf(fmaxf((f + 3.f) * (1.f / 6.f), 0.f), 1.f);
    float cr = lam * com[m * 2 + 0] + (1.f - lam) * er;
    float ci = lam * com[m * 2 + 1] + (1.f - lam) * ei;
    float g = (m == 0) ? (1.f / 1024.f) : (2.f / 1024.f);
    cmix[t] = make_float2(g * cr, g * ci);
}

// Fb (128 x 1024, B^T layout): row 2k = cos(2*pi*k*s/1024), row 2k+1 = -sin(...)
__global__ __launch_bounds__(256) void build_fb(bf16* __restrict__ Fb) {
    int t = blockIdx.x * 256 + threadIdx.x;   // 131072
    int rr = t >> 10, s = t & 1023;
    int k = rr >> 1;
    int ph = (k * s) & 1023;                  // exact integer phase reduction
    float ang = (float)ph * 6.1359231515425649e-3f;  // 2*pi/1024
    float v = (rr & 1) ? -sinf(ang) : cosf(ang);
    Fb[t] = (bf16)v;
}

// Bcat (1024 x 1152): cols 0..1023 = w[j][c]; col 1024+2k = cos(2*pi*k*j/1024), +2k+1 = -sin
__global__ __launch_bounds__(256) void build_bcat(const float* __restrict__ w,
                                                  bf16* __restrict__ out) {
    int t = blockIdx.x * 256 + threadIdx.x;   // 1024*1152
    if (t >= 1024 * 1152) return;
    int j = t / 1152, c = t % 1152;
    float v;
    if (c < 1024) {
        v = w[j * 1024 + c];
    } else {
        int cc = c - 1024, k = cc >> 1;
        int ph = (k * j) & 1023;
        float ang = (float)ph * 6.1359231515425649e-3f;
        v = (cc & 1) ? -sinf(ang) : cosf(ang);
    }
    out[t] = (bf16)v;
}

__global__ __launch_bounds__(256) void convert_bf16(const float* __restrict__ in,
                                                    bf16* __restrict__ out, int n) {
    int t = blockIdx.x * 256 + threadIdx.x;
    if (t < n) out[t] = (bf16)in[t];
}

// A0[n][0:512] = x_chunk[n*512 + s];  A0[n][512+s] = s/511   (n local to chunk)
__global__ __launch_bounds__(256) void build_a0(const float* __restrict__ x,
                                                bf16* __restrict__ A0) {
    int t = blockIdx.x * 256 + threadIdx.x;   // rows*128
    int n = t >> 7, part = t & 127;
    bf16x8 o;
    if (part < 64) {
        const float4* xp = (const float4*)(x + ((size_t)n * 512 + part * 8));
        float4 a = xp[0], b = xp[1];
        o[0] = (bf16)a.x; o[1] = (bf16)a.y; o[2] = (bf16)a.z; o[3] = (bf16)a.w;
        o[4] = (bf16)b.x; o[5] = (bf16)b.y; o[6] = (bf16)b.z; o[7] = (bf16)b.w;
        *(bf16x8*)(A0 + (size_t)n * 1024 + part * 8) = o;
    } else {
        int s0 = (part - 64) * 8;
        #pragma unroll
        for (int j = 0; j < 8; ++j) o[j] = (bf16)((float)(s0 + j) * (1.0f / 511.0f));
        *(bf16x8*)(A0 + (size_t)n * 1024 + 512 + s0) = o;
    }
}

// ---------------- GEMM: C = A @ Bt^T (+bias)(+act | +mix)  ----------------
// A (M x K) bf16 row-major lda; Bt (N x K) bf16 row-major ldb. 128x128 tile, BK=64,
// 4 waves (2x2), each wave 64x64 via 4x4 frags of mfma_f32_16x16x32_bf16.
// MIX epilogue: N==128 analysis output; even col 2k holds Xr, odd 2k+1 holds Xi
// (adjacent cols = adjacent lanes); Ymix[2k]=Xr*cr-Xi*ci, [2k+1]=Xr*ci+Xi*cr.
// row0 = global row offset of this chunk (for e = global_row % 16); chunk sizes are
// multiples of 128 so e == (local_row & 15).
template<int ACT, int MIX, int OUTF32>
__global__ __launch_bounds__(256)
void gemm_bt(const bf16* __restrict__ A, int lda,
             const bf16* __restrict__ Bt, int ldb,
             const float* __restrict__ bias,
             void* __restrict__ Cout, int ldc,
             const float2* __restrict__ cmix,
             int M, int N, int K) {
    __shared__ bf16 sA[128 * 64];
    __shared__ bf16 sB[128 * 64];
    const int tid = threadIdx.x;
    const int wave = tid >> 6;
    const int lane = tid & 63;
    const int wm = wave >> 1, wn = wave & 1;
    const int rowA0 = blockIdx.x * 128;
    const int rowB0 = blockIdx.y * 128;

    f32x4 acc[4][4];
    #pragma unroll
    for (int m = 0; m < 4; ++m)
        #pragma unroll
        for (int n = 0; n < 4; ++n)
            acc[m][n] = f32x4{0.f, 0.f, 0.f, 0.f};

    const int srow = wave * 32 + (lane >> 3);
    const int scol = (lane & 7) * 8;
    const bf16* gA = A + (size_t)(rowA0 + srow) * lda + scol;
    const bf16* gB = Bt + (size_t)(rowB0 + srow) * ldb + scol;
    bf16* lA = &sA[(wave * 32) * 64];
    bf16* lB = &sB[(wave * 32) * 64];

    for (int k0 = 0; k0 < K; k0 += 64) {
        __syncthreads();
        #pragma unroll
        for (int i = 0; i < 4; ++i) {
            gl_lds16(gA + (size_t)i * 8 * lda + k0, lA + i * 8 * 64);
            gl_lds16(gB + (size_t)i * 8 * ldb + k0, lB + i * 8 * 64);
        }
        __syncthreads();
        #pragma unroll
        for (int kk = 0; kk < 64; kk += 32) {
            bf16x8 af[4], bfr[4];
            #pragma unroll
            for (int m = 0; m < 4; ++m)
                af[m] = *(const bf16x8*)&sA[(wm * 64 + m * 16 + (lane & 15)) * 64 + kk + ((lane >> 4) * 8)];
            #pragma unroll
            for (int n = 0; n < 4; ++n)
                bfr[n] = *(const bf16x8*)&sB[(wn * 64 + n * 16 + (lane & 15)) * 64 + kk + ((lane >> 4) * 8)];
            #pragma unroll
            for (int m = 0; m < 4; ++m)
                #pragma unroll
                for (int n = 0; n < 4; ++n)
                    acc[m][n] = __builtin_amdgcn_mfma_f32_16x16x32_bf16(af[m], bfr[n], acc[m][n], 0, 0, 0);
        }
    }

    const int rowb = rowA0 + wm * 64;
    if (MIX) {
        #pragma unroll
        for (int m = 0; m < 4; ++m) {
            #pragma unroll
            for (int n = 0; n < 4; ++n) {
                int col = wn * 64 + n * 16 + (lane & 15);   // 0..127, parity == lane parity
                int k = col >> 1;
                #pragma unroll
                for (int r = 0; r < 4; ++r) {
                    float v = acc[m][n][r];
                    float p = __shfl_xor(v, 1);
                    int row = rowb + m * 16 + (lane >> 4) * 4 + r;
                    float2 c = cmix[(row & 15) * 64 + k];
                    float val = v * c.x + (((lane & 1) == 0) ? -p * c.y : p * c.y);
                    ((bf16*)Cout)[(size_t)row * ldc + col] = (bf16)val;
                }
            }
        }
    } else {
        const int colb = rowB0 + wn * 64;
        #pragma unroll
        for (int m = 0; m < 4; ++m) {
            #pragma unroll
            for (int n = 0; n < 4; ++n) {
                int col = colb + n * 16 + (lane & 15);
                float bv = bias ? bias[col] : 0.f;
                #pragma unroll
                for (int r = 0; r < 4; ++r) {
                    int row = rowb + m * 16 + (lane >> 4) * 4 + r;
                    float v = acc[m][n][r] + bv;
                    if (ACT) v = swishf(v);
                    if (OUTF32) ((float*)Cout)[(size_t)row * ldc + col] = v;
                    else        ((bf16*)Cout)[(size_t)row * ldc + col] = (bf16)v;
                }
            }
        }
    }
}

// ---------------- fused fc1 + swish + fc2 ----------------
// H (rows x 1024 fp32). Per block: stage fc2_w (8x2048 fp32, 64KB LDS), 16 rows.
// Phase 1: thread computes s[j], j = tid*8..tid*8+7 (g = 2*tid, 2*tid+1) -> LDS.
// Phase 2: o8 = tid>>5, 32-lane strided dot + shfl reduce.
__global__ __launch_bounds__(256) void fc_fused(const float* __restrict__ H,
                                                const float* __restrict__ w1,
                                                const float* __restrict__ b1,
                                                const float* __restrict__ w2,
                                                const float* __restrict__ b2,
                                                float* __restrict__ out) {
    __shared__ float sw2[8][2048];
    __shared__ float ss[2048];
    int tid = threadIdx.x;
    for (int i = tid; i < 8 * 2048; i += 256) sw2[i >> 11][i & 2047] = w2[i];

    float wv[16];
    const float4* w1p = (const float4*)(w1 + tid * 16);
    *(float4*)&wv[0]  = w1p[0];
    *(float4*)&wv[4]  = w1p[1];
    *(float4*)&wv[8]  = w1p[2];
    *(float4*)&wv[12] = w1p[3];
    float bb[8];
    const float4* b1p = (const float4*)(b1 + tid * 8);
    *(float4*)&bb[0] = b1p[0];
    *(float4*)&bb[4] = b1p[1];
    __syncthreads();

    for (int r = 0; r < 16; ++r) {
        int n = blockIdx.x * 16 + r;
        const float* h = H + (size_t)n * 1024;
        float4 hv = *(const float4*)(h + tid * 4);
        float hh[4] = {hv.x, hv.y, hv.z, hv.w};
        #pragma unroll
        for (int jj = 0; jj < 8; ++jj) {
            float h0 = hh[(jj >> 2) * 2];
            float h1 = hh[(jj >> 2) * 2 + 1];
            float t = h0 * wv[2 * jj] + h1 * wv[2 * jj + 1] + bb[jj];
            ss[tid * 8 + jj] = swishf(t);
        }
        __syncthreads();
        int o8 = tid >> 5, l5 = tid & 31;
        float p = 0.f;
        #pragma unroll 8
        for (int i = 0; i < 64; ++i) {
            int j = l5 + 32 * i;
            p += ss[j] * sw2[o8][j];
        }
        #pragma unroll
        for (int msk = 1; msk < 32; msk <<= 1) p += __shfl_xor(p, msk);
        if (l5 == 0) out[(size_t)n * 8 + o8] = p + b2[o8];
        __syncthreads();
    }
}

// ---------------- launch ----------------

extern "C" void kernel_launch(void* const* d_in, const int* in_sizes, int n_in,
                              void* d_out, int out_size, void* d_ws, size_t ws_size,
                              hipStream_t stream) {
    const float* x     = (const float*)d_in[0];
    const float* codes = (const float*)d_in[1];
    const float* p_w   = (const float*)d_in[2];
    const float* p_b   = (const float*)d_in[3];
    const float* com0  = (const float*)d_in[4];
    const float* code0 = (const float*)d_in[5];
    const float* filt0 = (const float*)d_in[6];
    const float* com1  = (const float*)d_in[7];
    const float* code1 = (const float*)d_in[8];
    const float* filt1 = (const float*)d_in[9];
    const float* w0_w  = (const float*)d_in[10];
    const float* w0_b  = (const float*)d_in[11];
    const float* w1_w  = (const float*)d_in[12];
    const float* w1_b  = (const float*)d_in[13];
    const float* fc1w  = (const float*)d_in[14];
    const float* fc1b  = (const float*)d_in[15];
    const float* fc2w  = (const float*)d_in[16];
    const float* fc2b  = (const float*)d_in[17];
    float* out = (float*)d_out;

    // ---- fixed region (weights), ~6.77 MB at front of workspace ----
    char* ws = (char*)d_ws;
    bf16*  pwb  = (bf16*)(ws + 0);               // 1024*1024*2   = 2,097,152
    bf16*  B0   = (bf16*)(ws + 2097152);         // 1024*1152*2   = 2,359,296
    bf16*  B1   = (bf16*)(ws + 4456448);         // 2,359,296
    bf16*  Fb   = (bf16*)(ws + 6815744);         // 128*1024*2    = 262,144
    float2* cm0 = (float2*)(ws + 7077888);       // 8,192
    float2* cm1 = (float2*)(ws + 7086080);       // 8,192
    const size_t CB = 7094272;                   // chunk region base

    // ---- choose row-chunk size R (multiple of 128) from ws_size ----
    // per-row bytes: AH region max(A0 bf16 2048, H3 f32 4096) = 4096; A1cat 2304; A2cat 2304
    const size_t PER_ROW = 4096 + 2304 + 2304;   // 8704
    long rmax = 0;
    if (ws_size > CB) rmax = (long)((ws_size - CB) / PER_ROW) / 128 * 128;
    if (rmax > 16384) rmax = 16384;              // cap: peak footprint ~150 MB
    if (rmax < 128) {                            // cannot run -> clean numeric fail, no OOB
        hipMemsetAsync(d_out, 0, (size_t)out_size * sizeof(float), stream);
        return;
    }
    const int R = (int)rmax;

    // ---- build weights once ----
    build_cmix<<<4, 256, 0, stream>>>(codes, com0, code0, filt0, cm0);
    build_cmix<<<4, 256, 0, stream>>>(codes, com1, code1, filt1, cm1);
    build_fb<<<512, 256, 0, stream>>>(Fb);
    build_bcat<<<4608, 256, 0, stream>>>(w0_w, B0);
    build_bcat<<<4608, 256, 0, stream>>>(w1_w, B1);
    convert_bf16<<<4096, 256, 0, stream>>>(p_w, pwb, 1024 * 1024);

    // ---- row chunks ----
    char* cb = ws + CB;
    for (int row0 = 0; row0 < N_ROWS; row0 += R) {
        const int r = (N_ROWS - row0 < R) ? (N_ROWS - row0) : R;   // multiple of 128
        bf16*  A0 = (bf16*)cb;                                     // r*2048 B (in r*4096 B region)
        float* H3 = (float*)cb;                                    // r*4096 B (same region, A0 dead)
        bf16*  A1 = (bf16*)(cb + (size_t)R * 4096);                // r*2304 B
        bf16*  A2 = (bf16*)(cb + (size_t)R * 4096 + (size_t)R * 2304);

        build_a0<<<r / 2, 256, 0, stream>>>(x + (size_t)row0 * 512, A0);

        // h1 = A0 @ p_w^T + p_b  -> A1cat[:, 0:1024]
        gemm_bt<0, 0, 0><<<dim3(r / 128, 8), 256, 0, stream>>>(
            A0, 1024, pwb, 1024, p_b, (void*)A1, 1152, nullptr, r, 1024, 1024);
        // Ymix0 -> A1cat[:, 1024:1152]
        gemm_bt<0, 1, 0><<<dim3(r / 128, 1), 256, 0, stream>>>(
            A1, 1152, Fb, 1024, nullptr, (void*)(A1 + 1024), 1152, cm0, r, 128, 1024);
        // h2 = swish(A1cat @ Bcat0^T + w0_b) -> A2cat[:, 0:1024]
        gemm_bt<1, 0, 0><<<dim3(r / 128, 8), 256, 0, stream>>>(
            A1, 1152, B0, 1152, w0_b, (void*)A2, 1152, nullptr, r, 1024, 1152);
        // Ymix1 -> A2cat[:, 1024:1152]
        gemm_bt<0, 1, 0><<<dim3(r / 128, 1), 256, 0, stream>>>(
            A2, 1152, Fb, 1024, nullptr, (void*)(A2 + 1024), 1152, cm1, r, 128, 1024);
        // H3 = A2cat @ Bcat1^T + w1_b (fp32, no act; overwrites A0 region)
        gemm_bt<0, 0, 1><<<dim3(r / 128, 8), 256, 0, stream>>>(
            A2, 1152, B1, 1152, w1_b, (void*)H3, 1024, nullptr, r, 1024, 1152);
        // out = fc2(swish(fc1(H3)))
        fc_fused<<<r / 16, 256, 0, stream>>>(H3, fc1w, fc1b, fc2w, fc2b, out + (size_t)row0 * 8);
    }
}